// Round 1
// baseline (322.909 us; speedup 1.0000x reference)
//
#include <hip/hip_runtime.h>
#include <math.h>

#define LL 512
#define HH 12
#define DM 384
#define DPAIR 128

#define SCALAR_SCALE 0.14433756729740643f   /* (3*16)^-0.5 */
#define POINT_SCALE  0.13608276348795434f   /* (3*4*4.5)^-0.5 */
#define PAIR_SCALE   0.5773502691896258f    /* 3^-0.5 */

__device__ __forceinline__ float softplusf(float w) {
  return (w > 20.f) ? w : log1pf(expf(w));
}

// ---------------- Kernel 1: QKV projections + point rotation ----------------
// grid (128, 2): x = row tile (4 rows), y = 0 -> scalar qkv, 1 -> point qkv
__global__ __launch_bounds__(256) void k_qkv(
    const float* __restrict__ x, const float* __restrict__ Ws,
    const float* __restrict__ Wp, const float* __restrict__ rot,
    const float* __restrict__ trans,
    float* __restrict__ qs, float* __restrict__ ks_, float* __restrict__ vs,
    float* __restrict__ qp, float* __restrict__ kp, float* __restrict__ vp)
{
  __shared__ float xs[4][DM];
  __shared__ float rawp[4][576];
  const int l0 = blockIdx.x * 4;
  const int half = blockIdx.y;
  for (int idx = threadIdx.x; idx < 4 * DM; idx += 256)
    xs[idx / DM][idx % DM] = x[(l0 + idx / DM) * DM + idx % DM];
  __syncthreads();
  const float* __restrict__ W = half ? Wp : Ws;
  for (int col = threadIdx.x; col < 576; col += 256) {
    float a0 = 0.f, a1 = 0.f, a2 = 0.f, a3 = 0.f;
    for (int k4 = 0; k4 < DM / 4; ++k4) {
      const int k = k4 * 4;
      const float w0 = W[(k + 0) * 576 + col];
      const float w1 = W[(k + 1) * 576 + col];
      const float w2 = W[(k + 2) * 576 + col];
      const float w3 = W[(k + 3) * 576 + col];
      const float4 x0 = *(const float4*)&xs[0][k];
      const float4 x1 = *(const float4*)&xs[1][k];
      const float4 x2 = *(const float4*)&xs[2][k];
      const float4 x3 = *(const float4*)&xs[3][k];
      a0 += x0.x * w0 + x0.y * w1 + x0.z * w2 + x0.w * w3;
      a1 += x1.x * w0 + x1.y * w1 + x1.z * w2 + x1.w * w3;
      a2 += x2.x * w0 + x2.y * w1 + x2.z * w2 + x2.w * w3;
      a3 += x3.x * w0 + x3.y * w1 + x3.z * w2 + x3.w * w3;
    }
    float acc[4] = {a0, a1, a2, a3};
    if (!half) {
      const int part = col / 192;
      const int h = (col % 192) / 16;
      const int d = col % 16;
      float* dst = part == 0 ? qs : (part == 1 ? ks_ : vs);
      #pragma unroll
      for (int r = 0; r < 4; ++r) dst[((h * LL) + l0 + r) * 16 + d] = acc[r];
    } else {
      #pragma unroll
      for (int r = 0; r < 4; ++r) rawp[r][col] = acc[r];
    }
  }
  if (half) {
    __syncthreads();
    for (int t = threadIdx.x; t < 4 * 192; t += 256) {
      const int r = t / 192, hp = t % 192;
      const int h = hp >> 4, p = hp & 15;
      const int l = l0 + r;
      const float c0 = rawp[r][hp * 3 + 0];
      const float c1 = rawp[r][hp * 3 + 1];
      const float c2 = rawp[r][hp * 3 + 2];
      const float* R = rot + l * 9;
      const float o0 = c0 * R[0] + c1 * R[3] + c2 * R[6] + trans[l * 3 + 0];
      const float o1 = c0 * R[1] + c1 * R[4] + c2 * R[7] + trans[l * 3 + 1];
      const float o2 = c0 * R[2] + c1 * R[5] + c2 * R[8] + trans[l * 3 + 2];
      float* dst;
      if (p < 4)      dst = qp + ((h * LL) + l) * 12 + p * 3;
      else if (p < 8) dst = kp + ((h * LL) + l) * 12 + (p - 4) * 3;
      else            dst = vp + ((h * LL) + l) * 24 + (p - 8) * 3;
      dst[0] = o0; dst[1] = o1; dst[2] = o2;
    }
  }
}

// ---------------- Kernel 2: fused logits + softmax + weighted sums ----------
// grid 512 (one block per query row i), 512 threads
__global__ __launch_bounds__(512) void k_attn(
    const float* __restrict__ pr, const float* __restrict__ Wpair,
    const float* __restrict__ bpair, const float* __restrict__ pwraw,
    const float* __restrict__ rot, const float* __restrict__ trans,
    const float* __restrict__ qs, const float* __restrict__ ks_,
    const float* __restrict__ vs, const float* __restrict__ qp,
    const float* __restrict__ kp, const float* __restrict__ vp,
    float* __restrict__ results)
{
  __shared__ float lg[LL * HH];     // logits, then attn, layout [j][h]
  __shared__ float wpT[HH * 132];   // W_pair transposed, padded
  __shared__ float qsi[HH * 16];
  __shared__ float qpi[HH * 12];
  __shared__ float bp[HH], pwv[HH];
  const int i = blockIdx.x;
  const int tid = threadIdx.x;

  for (int t = tid; t < DPAIR * HH; t += 512) {
    const int k = t / HH, h = t % HH;
    wpT[h * 132 + k] = Wpair[t];
  }
  for (int t = tid; t < HH * 16; t += 512) {
    const int h = t >> 4, d = t & 15;
    qsi[t] = qs[(h * LL + i) * 16 + d];
  }
  if (tid < HH * 12) {
    const int h = tid / 12;
    qpi[tid] = qp[(h * LL + i) * 12 + tid % 12];
  }
  if (tid < HH) {
    bp[tid] = bpair[tid];
    pwv[tid] = softplusf(pwraw[tid]);
  }
  __syncthreads();

  const float* __restrict__ pri = pr + (size_t)i * (LL * DPAIR);

  // phase 1: logits for all (j,h)
  for (int t = tid; t < LL * HH; t += 512) {
    const int j = t / HH, h = t % HH;
    const float4* prj = (const float4*)(pri + j * DPAIR);
    const float4* wph = (const float4*)(wpT + h * 132);
    float bias = 0.f;
    #pragma unroll 8
    for (int k4 = 0; k4 < DPAIR / 4; ++k4) {
      const float4 p4 = prj[k4];
      const float4 w4 = wph[k4];
      bias += p4.x * w4.x + p4.y * w4.y + p4.z * w4.z + p4.w * w4.w;
    }
    const float4* ksj = (const float4*)(ks_ + (h * LL + j) * 16);
    const float4* qsh = (const float4*)(qsi + h * 16);
    float s = 0.f;
    #pragma unroll
    for (int q4 = 0; q4 < 4; ++q4) {
      const float4 a = ksj[q4], b = qsh[q4];
      s += a.x * b.x + a.y * b.y + a.z * b.z + a.w * b.w;
    }
    const float4* kpj = (const float4*)(kp + (h * LL + j) * 12);
    const float4* qph = (const float4*)(qpi + h * 12);
    float dist = 0.f;
    #pragma unroll
    for (int q4 = 0; q4 < 3; ++q4) {
      const float4 a = kpj[q4], b = qph[q4];
      const float d0 = b.x - a.x, d1 = b.y - a.y, d2 = b.z - a.z, d3 = b.w - a.w;
      dist += d0 * d0 + d1 * d1 + d2 * d2 + d3 * d3;
    }
    lg[j * HH + h] = SCALAR_SCALE * s + PAIR_SCALE * (bias + bp[h])
                     - 0.5f * POINT_SCALE * pwv[h] * dist;
  }
  __syncthreads();

  // phase 2: softmax over j for each head
  const int wave = tid >> 6, lane = tid & 63;
  for (int h = wave; h < HH; h += 8) {
    float vals[8];
    float m = -1e30f;
    #pragma unroll
    for (int r = 0; r < 8; ++r) {
      vals[r] = lg[(lane + r * 64) * HH + h];
      m = fmaxf(m, vals[r]);
    }
    #pragma unroll
    for (int off = 32; off > 0; off >>= 1) m = fmaxf(m, __shfl_xor(m, off));
    float ssum = 0.f;
    #pragma unroll
    for (int r = 0; r < 8; ++r) { vals[r] = expf(vals[r] - m); ssum += vals[r]; }
    #pragma unroll
    for (int off = 32; off > 0; off >>= 1) ssum += __shfl_xor(ssum, off);
    const float inv = 1.f / ssum;
    #pragma unroll
    for (int r = 0; r < 8; ++r) lg[(lane + r * 64) * HH + h] = vals[r] * inv;
  }
  __syncthreads();

  float* __restrict__ resrow = results + (size_t)i * 2112;

  // phase 3b: res_s (12*16)
  for (int t = tid; t < HH * 16; t += 512) {
    const int h = t >> 4, d = t & 15;
    float acc = 0.f;
    for (int j = 0; j < LL; ++j) acc += lg[j * HH + h] * vs[(h * LL + j) * 16 + d];
    resrow[t] = acc;
  }
  // phase 3c: res_p + inverse rotation + norm (12*8)
  for (int t = tid; t < HH * 8; t += 512) {
    const int h = t >> 3, p = t & 7;
    float a0 = 0.f, a1 = 0.f, a2 = 0.f;
    const float* vph = vp + (size_t)(h * LL) * 24 + p * 3;
    for (int j = 0; j < LL; ++j) {
      const float a = lg[j * HH + h];
      const float* v = vph + j * 24;
      a0 += a * v[0]; a1 += a * v[1]; a2 += a * v[2];
    }
    a0 -= trans[i * 3 + 0]; a1 -= trans[i * 3 + 1]; a2 -= trans[i * 3 + 2];
    const float* R = rot + i * 9;
    const float o0 = a0 * R[0] + a1 * R[1] + a2 * R[2];
    const float o1 = a0 * R[3] + a1 * R[4] + a2 * R[5];
    const float o2 = a0 * R[6] + a1 * R[7] + a2 * R[8];
    resrow[192 + t * 3 + 0] = o0;
    resrow[192 + t * 3 + 1] = o1;
    resrow[192 + t * 3 + 2] = o2;
    resrow[480 + t] = sqrtf(o0 * o0 + o1 * o1 + o2 * o2 + 1e-8f);
  }
  // phase 3a: res_pair (12 * 64 float2 tasks)
  for (int t = tid; t < HH * 64; t += 512) {
    const int h = t >> 6, d2 = t & 63;
    const float2* p2 = (const float2*)pri + d2;
    float s0 = 0.f, s1 = 0.f;
    for (int j = 0; j < LL; ++j) {
      const float a = lg[j * HH + h];
      const float2 v = p2[(size_t)j * 64];
      s0 += a * v.x; s1 += a * v.y;
    }
    resrow[576 + h * 128 + d2 * 2 + 0] = s0;
    resrow[576 + h * 128 + d2 * 2 + 1] = s1;
  }
}

// ---------------- Kernel 3a: output GEMM, K-split partials ------------------
// grid (64, 4): x = 8-row tile, y = K tile of 528
__global__ __launch_bounds__(384) void k_out1(
    const float* __restrict__ results, const float* __restrict__ Wout,
    float* __restrict__ partial)
{
  __shared__ float rs[8 * 528];
  const int l0 = blockIdx.x * 8;
  const int k0 = blockIdx.y * 528;
  for (int idx = threadIdx.x; idx < 8 * 528; idx += 384) {
    const int r = idx / 528, kk = idx % 528;
    rs[idx] = results[(size_t)(l0 + r) * 2112 + k0 + kk];
  }
  __syncthreads();
  const int col = threadIdx.x;
  float acc[8] = {0.f, 0.f, 0.f, 0.f, 0.f, 0.f, 0.f, 0.f};
  for (int k4 = 0; k4 < 132; ++k4) {
    const int kk = k4 * 4;
    const float w0 = Wout[(size_t)(k0 + kk + 0) * 384 + col];
    const float w1 = Wout[(size_t)(k0 + kk + 1) * 384 + col];
    const float w2 = Wout[(size_t)(k0 + kk + 2) * 384 + col];
    const float w3 = Wout[(size_t)(k0 + kk + 3) * 384 + col];
    #pragma unroll
    for (int r = 0; r < 8; ++r) {
      const float4 xv = *(const float4*)&rs[r * 528 + kk];
      acc[r] += xv.x * w0 + xv.y * w1 + xv.z * w2 + xv.w * w3;
    }
  }
  #pragma unroll
  for (int r = 0; r < 8; ++r)
    partial[((size_t)blockIdx.y * LL + l0 + r) * 384 + col] = acc[r];
}

// ---------------- Kernel 3b: reduce partials + bias -------------------------
__global__ __launch_bounds__(256) void k_out2(
    const float* __restrict__ partial, const float* __restrict__ bout,
    float* __restrict__ out)
{
  const int e = blockIdx.x * 256 + threadIdx.x;
  const int c = e % 384;
  out[e] = bout[c] + partial[e] + partial[e + LL * 384]
         + partial[e + 2 * LL * 384] + partial[e + 3 * LL * 384];
}

extern "C" void kernel_launch(void* const* d_in, const int* in_sizes, int n_in,
                              void* d_out, int out_size, void* d_ws, size_t ws_size,
                              hipStream_t stream)
{
  const float* x     = (const float*)d_in[0];
  const float* prw   = (const float*)d_in[1];
  const float* rot   = (const float*)d_in[2];
  const float* trans = (const float*)d_in[3];
  const float* Ws    = (const float*)d_in[4];
  const float* Wp    = (const float*)d_in[5];
  const float* pw    = (const float*)d_in[6];
  const float* Wpair = (const float*)d_in[7];
  const float* bpair = (const float*)d_in[8];
  const float* Wout  = (const float*)d_in[9];
  const float* bout  = (const float*)d_in[10];

  float* ws = (float*)d_ws;
  float* qs      = ws;                   // 12*512*16 = 98304
  float* ks_     = qs + 98304;
  float* vs      = ks_ + 98304;
  float* qp      = vs + 98304;           // 12*512*12 = 73728
  float* kp      = qp + 73728;
  float* vp      = kp + 73728;           // 12*512*24 = 147456
  float* results = vp + 147456;          // 512*2112 = 1081344
  float* partial = results + 1081344;    // 4*512*384 = 786432
  float* out     = (float*)d_out;

  k_qkv<<<dim3(128, 2), 256, 0, stream>>>(x, Ws, Wp, rot, trans, qs, ks_, vs, qp, kp, vp);
  k_attn<<<512, 512, 0, stream>>>(prw, Wpair, bpair, pw, rot, trans,
                                  qs, ks_, vs, qp, kp, vp, results);
  k_out1<<<dim3(64, 4), 384, 0, stream>>>(results, Wout, partial);
  k_out2<<<768, 256, 0, stream>>>(partial, bout, out);
}

// Round 2
// 232.044 us; speedup vs baseline: 1.3916x; 1.3916x over previous
//
#include <hip/hip_runtime.h>
#include <math.h>

#define LL 512
#define HH 12
#define DM 384
#define DPAIR 128
#define TJ 64

#define SCALAR_SCALE 0.14433756729740643f   /* (3*16)^-0.5 */
#define POINT_SCALE  0.13608276348795434f   /* (3*4*4.5)^-0.5 */
#define PAIR_SCALE   0.5773502691896258f    /* 3^-0.5 */

__device__ __forceinline__ float softplusf(float w) {
  return (w > 20.f) ? w : log1pf(expf(w));
}

// ---------------- Kernel 1: QKV projections + point rotation ----------------
__global__ __launch_bounds__(256) void k_qkv(
    const float* __restrict__ x, const float* __restrict__ Ws,
    const float* __restrict__ Wp, const float* __restrict__ rot,
    const float* __restrict__ trans,
    float* __restrict__ qs, float* __restrict__ ks_, float* __restrict__ vs,
    float* __restrict__ qp, float* __restrict__ kp, float* __restrict__ vp)
{
  __shared__ float xs[4][DM];
  __shared__ float rawp[4][576];
  const int l0 = blockIdx.x * 4;
  const int half = blockIdx.y;
  for (int idx = threadIdx.x; idx < 4 * DM; idx += 256)
    xs[idx / DM][idx % DM] = x[(l0 + idx / DM) * DM + idx % DM];
  __syncthreads();
  const float* __restrict__ W = half ? Wp : Ws;
  for (int col = threadIdx.x; col < 576; col += 256) {
    float a0 = 0.f, a1 = 0.f, a2 = 0.f, a3 = 0.f;
    for (int k4 = 0; k4 < DM / 4; ++k4) {
      const int k = k4 * 4;
      const float w0 = W[(k + 0) * 576 + col];
      const float w1 = W[(k + 1) * 576 + col];
      const float w2 = W[(k + 2) * 576 + col];
      const float w3 = W[(k + 3) * 576 + col];
      const float4 x0 = *(const float4*)&xs[0][k];
      const float4 x1 = *(const float4*)&xs[1][k];
      const float4 x2 = *(const float4*)&xs[2][k];
      const float4 x3 = *(const float4*)&xs[3][k];
      a0 += x0.x * w0 + x0.y * w1 + x0.z * w2 + x0.w * w3;
      a1 += x1.x * w0 + x1.y * w1 + x1.z * w2 + x1.w * w3;
      a2 += x2.x * w0 + x2.y * w1 + x2.z * w2 + x2.w * w3;
      a3 += x3.x * w0 + x3.y * w1 + x3.z * w2 + x3.w * w3;
    }
    float acc[4] = {a0, a1, a2, a3};
    if (!half) {
      const int part = col / 192;
      const int h = (col % 192) / 16;
      const int d = col % 16;
      float* dst = part == 0 ? qs : (part == 1 ? ks_ : vs);
      #pragma unroll
      for (int r = 0; r < 4; ++r) dst[((h * LL) + l0 + r) * 16 + d] = acc[r];
    } else {
      #pragma unroll
      for (int r = 0; r < 4; ++r) rawp[r][col] = acc[r];
    }
  }
  if (half) {
    __syncthreads();
    for (int t = threadIdx.x; t < 4 * 192; t += 256) {
      const int r = t / 192, hp = t % 192;
      const int h = hp >> 4, p = hp & 15;
      const int l = l0 + r;
      const float c0 = rawp[r][hp * 3 + 0];
      const float c1 = rawp[r][hp * 3 + 1];
      const float c2 = rawp[r][hp * 3 + 2];
      const float* R = rot + l * 9;
      const float o0 = c0 * R[0] + c1 * R[3] + c2 * R[6] + trans[l * 3 + 0];
      const float o1 = c0 * R[1] + c1 * R[4] + c2 * R[7] + trans[l * 3 + 1];
      const float o2 = c0 * R[2] + c1 * R[5] + c2 * R[8] + trans[l * 3 + 2];
      float* dst;
      if (p < 4)      dst = qp + ((h * LL) + l) * 12 + p * 3;
      else if (p < 8) dst = kp + ((h * LL) + l) * 12 + (p - 4) * 3;
      else            dst = vp + ((h * LL) + l) * 24 + (p - 8) * 3;
      dst[0] = o0; dst[1] = o1; dst[2] = o2;
    }
  }
}

// -------- Kernel 2: single-pass pairwise: logits + online softmax + res_pair
// grid 512 (one block per query row i), 512 threads (8 waves)
__global__ __launch_bounds__(512) void k_pair_fused(
    const float* __restrict__ pr, const float* __restrict__ Wpair,
    const float* __restrict__ bpair, const float* __restrict__ pwraw,
    const float* __restrict__ qs, const float* __restrict__ ks_,
    const float* __restrict__ qp, const float* __restrict__ kp,
    float* __restrict__ logits, float* __restrict__ results)
{
  __shared__ float prs[TJ][132];     // staged pairwise tile (padded)
  __shared__ float lt[TJ][12];       // logits, then unnormalized p
  __shared__ float red[12 * 128];    // res_pair cross-wave reduction
  __shared__ float wpT[12 * 132];    // W_pair transposed
  __shared__ float qsi[12 * 16];
  __shared__ float qpi[12 * 12];
  __shared__ float bp[12], pwv[12];
  __shared__ float fh[12];           // per-tile rescale factors
  __shared__ float mh[12], lh[12];   // running max / sum

  const int i = blockIdx.x;
  const int tid = threadIdx.x;
  const int wv = tid >> 6, lane = tid & 63;

  for (int t = tid; t < DPAIR * 12; t += 512) {
    const int k = t / 12, h = t % 12;
    wpT[h * 132 + k] = Wpair[t];
  }
  for (int t = tid; t < 12 * 16; t += 512)
    qsi[t] = qs[((t >> 4) * LL + i) * 16 + (t & 15)];
  if (tid < 144) qpi[tid] = qp[((tid / 12) * LL + i) * 12 + tid % 12];
  if (tid < 12) {
    bp[tid] = bpair[tid];
    pwv[tid] = softplusf(pwraw[tid]);
    mh[tid] = -1e30f; lh[tid] = 0.f;
  }

  float accp[12][2];
  #pragma unroll
  for (int h = 0; h < 12; ++h) { accp[h][0] = 0.f; accp[h][1] = 0.f; }

  const float* __restrict__ pri = pr + (size_t)i * (LL * DPAIR);
  __syncthreads();

  for (int j0 = 0; j0 < LL; j0 += TJ) {
    // stage 64x128 pairwise tile, coalesced float4
    #pragma unroll
    for (int p = 0; p < 4; ++p) {
      const int idx = tid + p * 512;      // float4 index, 2048 total
      const int row = idx >> 5;           // 32 float4 per row
      const int col = (idx & 31) << 2;
      const float4 v = ((const float4*)(pri + (size_t)(j0 + row) * DPAIR))[idx & 31];
      *(float4*)&prs[row][col] = v;
    }
    __syncthreads();

    // logits for this tile (64 j x 12 h = 768 tasks)
    for (int t = tid; t < TJ * 12; t += 512) {
      const int j = t / 12, h = t % 12;
      const float4* prj = (const float4*)&prs[j][0];
      const float4* wph = (const float4*)&wpT[h * 132];
      float bias = 0.f;
      #pragma unroll 8
      for (int k4 = 0; k4 < DPAIR / 4; ++k4) {
        const float4 p4 = prj[k4];
        const float4 w4 = wph[k4];
        bias += p4.x * w4.x + p4.y * w4.y + p4.z * w4.z + p4.w * w4.w;
      }
      const float4* ksj = (const float4*)(ks_ + (size_t)(h * LL + j0 + j) * 16);
      const float4* qsh = (const float4*)(qsi + h * 16);
      float s = 0.f;
      #pragma unroll
      for (int q4 = 0; q4 < 4; ++q4) {
        const float4 a = ksj[q4], b = qsh[q4];
        s += a.x * b.x + a.y * b.y + a.z * b.z + a.w * b.w;
      }
      const float4* kpj = (const float4*)(kp + (size_t)(h * LL + j0 + j) * 12);
      const float4* qph = (const float4*)(qpi + h * 12);
      float dist = 0.f;
      #pragma unroll
      for (int q4 = 0; q4 < 3; ++q4) {
        const float4 a = kpj[q4], b = qph[q4];
        const float d0 = b.x - a.x, d1 = b.y - a.y, d2 = b.z - a.z, d3 = b.w - a.w;
        dist += d0 * d0 + d1 * d1 + d2 * d2 + d3 * d3;
      }
      const float L = SCALAR_SCALE * s + PAIR_SCALE * (bias + bp[h])
                      - 0.5f * POINT_SCALE * pwv[h] * dist;
      lt[j][h] = L;
      logits[((size_t)i * LL + j0 + j) * 12 + h] = L;
    }
    __syncthreads();

    // per-head online softmax partials (wave wv handles heads wv, wv+8)
    for (int h = wv; h < 12; h += 8) {
      const float v = lt[lane][h];
      float m = v;
      #pragma unroll
      for (int off = 32; off > 0; off >>= 1) m = fmaxf(m, __shfl_xor(m, off));
      const float mo = mh[h];
      const float mn = fmaxf(mo, m);
      const float pv = __expf(v - mn);
      lt[lane][h] = pv;
      float s = pv;
      #pragma unroll
      for (int off = 32; off > 0; off >>= 1) s += __shfl_xor(s, off);
      if (lane == 0) {
        const float f = __expf(mo - mn);
        fh[h] = f;
        lh[h] = lh[h] * f + s;
        mh[h] = mn;
      }
    }
    __syncthreads();

    // rescale accumulators + accumulate this tile (wave wv owns rows wv*8..+7)
    float f_[12];
    #pragma unroll
    for (int h = 0; h < 12; ++h) f_[h] = fh[h];
    #pragma unroll
    for (int h = 0; h < 12; ++h) { accp[h][0] *= f_[h]; accp[h][1] *= f_[h]; }
    #pragma unroll
    for (int r = 0; r < 8; ++r) {
      const int j = wv * 8 + r;
      const float2 pv2 = *(const float2*)&prs[j][lane * 2];
      #pragma unroll
      for (int h = 0; h < 12; ++h) {
        const float p = lt[j][h];
        accp[h][0] += p * pv2.x;
        accp[h][1] += p * pv2.y;
      }
    }
    __syncthreads();   // protect prs/lt before next tile
  }

  // cross-wave reduction of res_pair partials
  for (int w = 0; w < 8; ++w) {
    if (wv == w) {
      #pragma unroll
      for (int h = 0; h < 12; ++h) {
        float* slot = &red[h * 128 + lane * 2];
        if (w == 0) { slot[0] = accp[h][0]; slot[1] = accp[h][1]; }
        else        { slot[0] += accp[h][0]; slot[1] += accp[h][1]; }
      }
    }
    __syncthreads();
  }

  float* __restrict__ resrow = results + (size_t)i * 2112;
  for (int t = tid; t < 12 * 64; t += 512) {
    const int h = t >> 6, d2 = t & 63;
    const float inv = 1.f / lh[h];
    resrow[576 + h * 128 + d2 * 2 + 0] = red[h * 128 + d2 * 2 + 0] * inv;
    resrow[576 + h * 128 + d2 * 2 + 1] = red[h * 128 + d2 * 2 + 1] * inv;
  }
}

// -------- Kernel 3: softmax (from stored logits) + res_s + res_p ------------
__global__ __launch_bounds__(512) void k_attn_small(
    const float* __restrict__ logits, const float* __restrict__ rot,
    const float* __restrict__ trans, const float* __restrict__ vs,
    const float* __restrict__ vp, float* __restrict__ results)
{
  __shared__ float lg[LL * 12];
  const int i = blockIdx.x;
  const int tid = threadIdx.x;
  for (int t = tid; t < LL * 12; t += 512) lg[t] = logits[(size_t)i * (LL * 12) + t];
  __syncthreads();

  const int wave = tid >> 6, lane = tid & 63;
  for (int h = wave; h < 12; h += 8) {
    float vals[8];
    float m = -1e30f;
    #pragma unroll
    for (int r = 0; r < 8; ++r) {
      vals[r] = lg[(lane + r * 64) * 12 + h];
      m = fmaxf(m, vals[r]);
    }
    #pragma unroll
    for (int off = 32; off > 0; off >>= 1) m = fmaxf(m, __shfl_xor(m, off));
    float ssum = 0.f;
    #pragma unroll
    for (int r = 0; r < 8; ++r) { vals[r] = __expf(vals[r] - m); ssum += vals[r]; }
    #pragma unroll
    for (int off = 32; off > 0; off >>= 1) ssum += __shfl_xor(ssum, off);
    const float inv = 1.f / ssum;
    #pragma unroll
    for (int r = 0; r < 8; ++r) lg[(lane + r * 64) * 12 + h] = vals[r] * inv;
  }
  __syncthreads();

  float* __restrict__ resrow = results + (size_t)i * 2112;

  // res_s (12*16)
  for (int t = tid; t < 12 * 16; t += 512) {
    const int h = t >> 4, d = t & 15;
    float acc = 0.f;
    for (int j = 0; j < LL; ++j) acc += lg[j * 12 + h] * vs[(h * LL + j) * 16 + d];
    resrow[t] = acc;
  }
  // res_p + inverse rotation + norm (12*8)
  for (int t = tid; t < 12 * 8; t += 512) {
    const int h = t >> 3, p = t & 7;
    float a0 = 0.f, a1 = 0.f, a2 = 0.f;
    const float* vph = vp + (size_t)(h * LL) * 24 + p * 3;
    for (int j = 0; j < LL; ++j) {
      const float a = lg[j * 12 + h];
      const float* v = vph + j * 24;
      a0 += a * v[0]; a1 += a * v[1]; a2 += a * v[2];
    }
    a0 -= trans[i * 3 + 0]; a1 -= trans[i * 3 + 1]; a2 -= trans[i * 3 + 2];
    const float* R = rot + i * 9;
    const float o0 = a0 * R[0] + a1 * R[1] + a2 * R[2];
    const float o1 = a0 * R[3] + a1 * R[4] + a2 * R[5];
    const float o2 = a0 * R[6] + a1 * R[7] + a2 * R[8];
    resrow[192 + t * 3 + 0] = o0;
    resrow[192 + t * 3 + 1] = o1;
    resrow[192 + t * 3 + 2] = o2;
    resrow[480 + t] = sqrtf(o0 * o0 + o1 * o1 + o2 * o2 + 1e-8f);
  }
}

// ---------------- Kernel 4a: output GEMM, K-split partials ------------------
__global__ __launch_bounds__(384) void k_out1(
    const float* __restrict__ results, const float* __restrict__ Wout,
    float* __restrict__ partial)
{
  __shared__ float rs[8 * 528];
  const int l0 = blockIdx.x * 8;
  const int k0 = blockIdx.y * 528;
  for (int idx = threadIdx.x; idx < 8 * 528; idx += 384) {
    const int r = idx / 528, kk = idx % 528;
    rs[idx] = results[(size_t)(l0 + r) * 2112 + k0 + kk];
  }
  __syncthreads();
  const int col = threadIdx.x;
  float acc[8] = {0.f, 0.f, 0.f, 0.f, 0.f, 0.f, 0.f, 0.f};
  for (int k4 = 0; k4 < 132; ++k4) {
    const int kk = k4 * 4;
    const float w0 = Wout[(size_t)(k0 + kk + 0) * 384 + col];
    const float w1 = Wout[(size_t)(k0 + kk + 1) * 384 + col];
    const float w2 = Wout[(size_t)(k0 + kk + 2) * 384 + col];
    const float w3 = Wout[(size_t)(k0 + kk + 3) * 384 + col];
    #pragma unroll
    for (int r = 0; r < 8; ++r) {
      const float4 xv = *(const float4*)&rs[r * 528 + kk];
      acc[r] += xv.x * w0 + xv.y * w1 + xv.z * w2 + xv.w * w3;
    }
  }
  #pragma unroll
  for (int r = 0; r < 8; ++r)
    partial[((size_t)blockIdx.y * LL + l0 + r) * 384 + col] = acc[r];
}

// ---------------- Kernel 4b: reduce partials + bias -------------------------
__global__ __launch_bounds__(256) void k_out2(
    const float* __restrict__ partial, const float* __restrict__ bout,
    float* __restrict__ out)
{
  const int e = blockIdx.x * 256 + threadIdx.x;
  const int c = e % 384;
  out[e] = bout[c] + partial[e] + partial[e + LL * 384]
         + partial[e + 2 * LL * 384] + partial[e + 3 * LL * 384];
}

extern "C" void kernel_launch(void* const* d_in, const int* in_sizes, int n_in,
                              void* d_out, int out_size, void* d_ws, size_t ws_size,
                              hipStream_t stream)
{
  const float* x     = (const float*)d_in[0];
  const float* prw   = (const float*)d_in[1];
  const float* rot   = (const float*)d_in[2];
  const float* trans = (const float*)d_in[3];
  const float* Ws    = (const float*)d_in[4];
  const float* Wp    = (const float*)d_in[5];
  const float* pw    = (const float*)d_in[6];
  const float* Wpair = (const float*)d_in[7];
  const float* bpair = (const float*)d_in[8];
  const float* Wout  = (const float*)d_in[9];
  const float* bout  = (const float*)d_in[10];

  float* ws = (float*)d_ws;
  float* qs      = ws;                   // 12*512*16 = 98304
  float* ks_     = qs + 98304;
  float* vs      = ks_ + 98304;
  float* qp      = vs + 98304;           // 12*512*12 = 73728
  float* kp      = qp + 73728;
  float* vp      = kp + 73728;           // 12*512*24 = 147456
  float* results = vp + 147456;          // 512*2112 = 1081344
  float* partial = results + 1081344;    // 4*512*384 = 786432
  float* logits  = partial + 786432;     // 512*512*12 = 3145728 (12.6 MB)
  float* out     = (float*)d_out;

  k_qkv<<<dim3(128, 2), 256, 0, stream>>>(x, Ws, Wp, rot, trans, qs, ks_, vs, qp, kp, vp);
  k_pair_fused<<<512, 512, 0, stream>>>(prw, Wpair, bpair, pw, qs, ks_, qp, kp,
                                        logits, results);
  k_attn_small<<<512, 512, 0, stream>>>(logits, rot, trans, vs, vp, results);
  k_out1<<<dim3(64, 4), 384, 0, stream>>>(results, Wout, partial);
  k_out2<<<768, 256, 0, stream>>>(partial, bout, out);
}